// Round 5
// baseline (96.787 us; speedup 1.0000x reference)
//
#include <hip/hip_runtime.h>

static constexpr int   Bn      = 32;
static constexpr int   Tn      = 2000;
static constexpr int   Hn      = 512;
static constexpr int   Ln      = 256;     // max_label_len
static constexpr float kThresh = 0.95f;
static constexpr int   TCHUNK  = 40;
static constexpr int   NTCH    = Tn / TCHUNK;   // 50

// ---------------------------------------------------------------------------
// K1 scan: one block (one wave) per batch row; pure register recurrence
// (~12 cyc/step), double-buffered alpha loads, and the ONLY stores are one
// 8 B (integrate, fc) snapshot per 40-step chunk from lane 0. R2/R3 lesson:
// any per-step store inside the serial loop costs ~100 cyc/step in vmcnt.
// ---------------------------------------------------------------------------
__global__ __launch_bounds__(64) void cif_scan_kernel(
    const float* __restrict__ alphas,
    float2* __restrict__ meta,     // [Bn][NTCH]: chunk-start (integrate, bits(fc))
    int* __restrict__ fcnt) {      // [Bn]
  const int b = blockIdx.x;
  const float4* __restrict__ arow =
      reinterpret_cast<const float4*>(alphas + (size_t)b * Tn);
  constexpr int CV = TCHUNK / 4;   // 10 float4 per chunk

  float integrate = 0.0f;
  int   fc        = 0;

  float4 cur[CV], nxt[CV];
#pragma unroll
  for (int i = 0; i < CV; ++i) cur[i] = arow[i];

  for (int c = 0; c < NTCH; ++c) {
    if (c + 1 < NTCH) {
#pragma unroll
      for (int i = 0; i < CV; ++i) nxt[i] = arow[(c + 1) * CV + i];
    }
    if (threadIdx.x == 0)
      meta[b * NTCH + c] = make_float2(integrate, __int_as_float(fc));
#pragma unroll
    for (int i = 0; i < CV; ++i) {
      const float a4[4] = {cur[i].x, cur[i].y, cur[i].z, cur[i].w};
#pragma unroll
      for (int j = 0; j < 4; ++j) {
        const float integ = integrate + a4[j];    // reference op order
        const bool  fire  = integ > kThresh;
        integrate = fire ? (integ - 1.0f) : integ;
        fc += fire ? 1 : 0;
      }
    }
#pragma unroll
    for (int i = 0; i < CV; ++i) cur[i] = nxt[i];
  }
  if (threadIdx.x == 0) fcnt[b] = fc;
}

// ---------------------------------------------------------------------------
// K2 expand: 50 blocks (one per time-chunk); lane b replays the 40-step
// recurrence of row b from the BIT-EXACT chunk-start state and materializes
// per-step weights/segments in TIME-MAJOR layout: at each t the 32 lanes
// store w12[t][0..31] (256 B) and seg[t][0..31] (128 B) contiguously.
// Parallel across chunks, so these stores cost ~nothing (unlike R3, where
// the same stores sat inside the single serial scan wave).
// ---------------------------------------------------------------------------
__global__ __launch_bounds__(64) void cif_expand_kernel(
    const float* __restrict__ alphas,
    const float2* __restrict__ meta,
    float2* __restrict__ w12,      // [Tn][Bn]
    int* __restrict__ seg) {       // [Tn][Bn]
  const int tc = blockIdx.x;
  const int b  = threadIdx.x;
  if (b >= Bn) return;
  const int t0 = tc * TCHUNK;

  const float2 m  = meta[b * NTCH + tc];
  float integrate = m.x;
  int   fc        = __float_as_int(m.y);

  const float4* __restrict__ arow =
      reinterpret_cast<const float4*>(alphas + (size_t)b * Tn + t0);
  float av[TCHUNK];
#pragma unroll
  for (int i = 0; i < TCHUNK / 4; ++i) {
    const float4 v = arow[i];
    av[4 * i + 0] = v.x; av[4 * i + 1] = v.y;
    av[4 * i + 2] = v.z; av[4 * i + 3] = v.w;
  }

#pragma unroll
  for (int k = 0; k < TCHUNK; ++k) {
    const float a     = av[k];
    const float integ = integrate + a;            // reference op order
    const bool  fire  = integ > kThresh;
    const float cw    = fire ? (1.0f - integrate) : a;
    const float rem   = fire ? (a - cw) : 0.0f;
    w12[(size_t)(t0 + k) * Bn + b] = make_float2(cw, rem);
    seg[(size_t)(t0 + k) * Bn + b] = fc;
    integrate = fire ? (integ - 1.0f) : integ;
    fc += fire ? 1 : 0;
  }
}

// ---------------------------------------------------------------------------
// K3 accum (R3's fast version): grid (B, NTCH) x 128 threads; each thread
// owns 4 consecutive floats of the H=512 row (coalesced float4). Segments
// are monotone in t: accumulate in registers, flush on close. Only the
// chunk's first segment (receives previous chunk's tail) and the final open
// segment are shared -> atomicAdd; interior segments exclusive -> plain
// float4 store (out pre-zeroed). w12/seg reads are block-uniform broadcasts
// from the L2-resident workspace; hidden streams from L3.
// ---------------------------------------------------------------------------
__global__ __launch_bounds__(128) void cif_accum_kernel(
    const float* __restrict__ hidden,
    const float2* __restrict__ w12,   // [Tn][Bn]
    const int* __restrict__ seg,      // [Tn][Bn]
    const int* __restrict__ fcnt,
    float* __restrict__ out) {
  const int b   = blockIdx.x;
  const int tc  = blockIdx.y;
  const int t0  = tc * TCHUNK;
  const int t1  = t0 + TCHUNK;
  const int col = threadIdx.x * 4;

  const int fb    = fcnt[b];
  const int limit = fb < Ln ? fb : Ln;   // segments >= limit never emitted

  const float* hbase = hidden + (size_t)b * Tn * Hn + col;
  float*       obase = out    + (size_t)b * Ln * Hn + col;

  const int seg0 = seg[(size_t)t0 * Bn + b];

  float4 acc    = make_float4(0.f, 0.f, 0.f, 0.f);
  int    curseg = seg0;

  auto flush = [&](int sg, const float4& v, bool shared) {
    if (sg < limit) {
      float* o = obase + (size_t)sg * Hn;
      if (shared) {
        atomicAdd(o + 0, v.x);
        atomicAdd(o + 1, v.y);
        atomicAdd(o + 2, v.z);
        atomicAdd(o + 3, v.w);
      } else {
        *reinterpret_cast<float4*>(o) = v;   // exclusive: plain store
      }
    }
  };

  for (int t = t0; t < t1; ++t) {
    const int s = seg[(size_t)t * Bn + b];
    if (s != curseg) {               // fire with exactly-zero remainder
      flush(curseg, acc, curseg == seg0);
      acc    = make_float4(0.f, 0.f, 0.f, 0.f);
      curseg = s;
    }
    const float4 h = *reinterpret_cast<const float4*>(hbase + (size_t)t * Hn);
    const float2 w = w12[(size_t)t * Bn + b];
    acc.x += w.x * h.x;
    acc.y += w.x * h.y;
    acc.z += w.x * h.z;
    acc.w += w.x * h.w;
    if (w.y != 0.0f) {               // fire: close segment s, open s+1
      flush(s, acc, s == seg0);
      acc.x  = w.y * h.x;
      acc.y  = w.y * h.y;
      acc.z  = w.y * h.z;
      acc.w  = w.y * h.w;
      curseg = s + 1;
    }
  }
  flush(curseg, acc, true);          // open segment: may continue next chunk
}

extern "C" void kernel_launch(void* const* d_in, const int* in_sizes, int n_in,
                              void* d_out, int out_size, void* d_ws, size_t ws_size,
                              hipStream_t stream) {
  const float* hidden = (const float*)d_in[0];
  const float* alphas = (const float*)d_in[1];
  float* out = (float*)d_out;

  // ws layout: w12[T][B] float2 (512 KB) | seg[T][B] i32 (256 KB)
  //          | meta[B][NTCH] float2 (12.8 KB) | fcnt[B] i32
  float2* w12  = (float2*)d_ws;
  int*    segp = (int*)(w12 + (size_t)Bn * Tn);
  float2* meta = (float2*)(segp + (size_t)Bn * Tn);
  int*    fcnt = (int*)(meta + (size_t)Bn * NTCH);

  // Output must be zero (harness poisons with 0xAA; non-fired slots stay 0).
  hipMemsetAsync(d_out, 0, (size_t)out_size * sizeof(float), stream);

  cif_scan_kernel<<<Bn, 64, 0, stream>>>(alphas, meta, fcnt);
  cif_expand_kernel<<<NTCH, 64, 0, stream>>>(alphas, meta, w12, segp);

  dim3 grid(Bn, NTCH);
  cif_accum_kernel<<<grid, 128, 0, stream>>>(hidden, w12, segp, fcnt, out);
}

// Round 6
// 96.201 us; speedup vs baseline: 1.0061x; 1.0061x over previous
//
#include <hip/hip_runtime.h>

static constexpr int   Bn      = 32;
static constexpr int   Tn      = 2000;
static constexpr int   Hn      = 512;
static constexpr int   Ln      = 256;     // max_label_len
static constexpr float kThresh = 0.95f;
static constexpr int   TCHUNK  = 40;
static constexpr int   NTCH    = Tn / TCHUNK;   // 50

// ---------------------------------------------------------------------------
// K0 zero: grid-stride float4 zero of d_out. R5 lesson: hipMemsetAsync's
// rocclr fillBufferAligned runs at ~220 GB/s (tiny grid, 10% occupancy) and
// took 75 of our 97 µs. A plain full-grid store kernel does 16.8 MB in ~3 µs.
// ---------------------------------------------------------------------------
__global__ __launch_bounds__(256) void cif_zero_kernel(float4* __restrict__ p,
                                                       int n4) {
  const int stride = gridDim.x * blockDim.x;
  for (int i = blockIdx.x * blockDim.x + threadIdx.x; i < n4; i += stride)
    p[i] = make_float4(0.f, 0.f, 0.f, 0.f);
}

// ---------------------------------------------------------------------------
// K1 scan: one block (one wave) per batch row; pure register recurrence
// (~12 cyc/step), double-buffered alpha loads, and the ONLY stores are one
// 8 B (integrate, fc) snapshot per 40-step chunk from lane 0. R2/R3 lesson:
// any per-step store inside the serial loop costs ~100 cyc/step in vmcnt.
// ---------------------------------------------------------------------------
__global__ __launch_bounds__(64) void cif_scan_kernel(
    const float* __restrict__ alphas,
    float2* __restrict__ meta,     // [Bn][NTCH]: chunk-start (integrate, bits(fc))
    int* __restrict__ fcnt) {      // [Bn]
  const int b = blockIdx.x;
  const float4* __restrict__ arow =
      reinterpret_cast<const float4*>(alphas + (size_t)b * Tn);
  constexpr int CV = TCHUNK / 4;   // 10 float4 per chunk

  float integrate = 0.0f;
  int   fc        = 0;

  float4 cur[CV], nxt[CV];
#pragma unroll
  for (int i = 0; i < CV; ++i) cur[i] = arow[i];

  for (int c = 0; c < NTCH; ++c) {
    if (c + 1 < NTCH) {
#pragma unroll
      for (int i = 0; i < CV; ++i) nxt[i] = arow[(c + 1) * CV + i];
    }
    if (threadIdx.x == 0)
      meta[b * NTCH + c] = make_float2(integrate, __int_as_float(fc));
#pragma unroll
    for (int i = 0; i < CV; ++i) {
      const float a4[4] = {cur[i].x, cur[i].y, cur[i].z, cur[i].w};
#pragma unroll
      for (int j = 0; j < 4; ++j) {
        const float integ = integrate + a4[j];    // reference op order
        const bool  fire  = integ > kThresh;
        integrate = fire ? (integ - 1.0f) : integ;
        fc += fire ? 1 : 0;
      }
    }
#pragma unroll
    for (int i = 0; i < CV; ++i) cur[i] = nxt[i];
  }
  if (threadIdx.x == 0) fcnt[b] = fc;
}

// ---------------------------------------------------------------------------
// K2 expand: 50 blocks (one per time-chunk); lane b replays the 40-step
// recurrence of row b from the BIT-EXACT chunk-start state and materializes
// per-step weights/segments in TIME-MAJOR layout: at each t the 32 lanes
// store w12[t][0..31] (256 B) and seg[t][0..31] (128 B) contiguously.
// Parallel across chunks, so these stores cost ~nothing (unlike R3, where
// the same stores sat inside the single serial scan wave).
// ---------------------------------------------------------------------------
__global__ __launch_bounds__(64) void cif_expand_kernel(
    const float* __restrict__ alphas,
    const float2* __restrict__ meta,
    float2* __restrict__ w12,      // [Tn][Bn]
    int* __restrict__ seg) {       // [Tn][Bn]
  const int tc = blockIdx.x;
  const int b  = threadIdx.x;
  if (b >= Bn) return;
  const int t0 = tc * TCHUNK;

  const float2 m  = meta[b * NTCH + tc];
  float integrate = m.x;
  int   fc        = __float_as_int(m.y);

  const float4* __restrict__ arow =
      reinterpret_cast<const float4*>(alphas + (size_t)b * Tn + t0);
  float av[TCHUNK];
#pragma unroll
  for (int i = 0; i < TCHUNK / 4; ++i) {
    const float4 v = arow[i];
    av[4 * i + 0] = v.x; av[4 * i + 1] = v.y;
    av[4 * i + 2] = v.z; av[4 * i + 3] = v.w;
  }

#pragma unroll
  for (int k = 0; k < TCHUNK; ++k) {
    const float a     = av[k];
    const float integ = integrate + a;            // reference op order
    const bool  fire  = integ > kThresh;
    const float cw    = fire ? (1.0f - integrate) : a;
    const float rem   = fire ? (a - cw) : 0.0f;
    w12[(size_t)(t0 + k) * Bn + b] = make_float2(cw, rem);
    seg[(size_t)(t0 + k) * Bn + b] = fc;
    integrate = fire ? (integ - 1.0f) : integ;
    fc += fire ? 1 : 0;
  }
}

// ---------------------------------------------------------------------------
// K3 accum: grid (B, NTCH) x 128 threads; each thread owns 4 consecutive
// floats of the H=512 row (coalesced float4). Segments are monotone in t:
// accumulate in registers, flush on close. Only the chunk's first segment
// (receives previous chunk's tail) and the final open segment are shared ->
// atomicAdd; interior segments exclusive -> plain float4 store (out
// pre-zeroed). w12/seg reads are block-uniform broadcasts from the
// L2-resident workspace; hidden streams from L3.
// ---------------------------------------------------------------------------
__global__ __launch_bounds__(128) void cif_accum_kernel(
    const float* __restrict__ hidden,
    const float2* __restrict__ w12,   // [Tn][Bn]
    const int* __restrict__ seg,      // [Tn][Bn]
    const int* __restrict__ fcnt,
    float* __restrict__ out) {
  const int b   = blockIdx.x;
  const int tc  = blockIdx.y;
  const int t0  = tc * TCHUNK;
  const int t1  = t0 + TCHUNK;
  const int col = threadIdx.x * 4;

  const int fb    = fcnt[b];
  const int limit = fb < Ln ? fb : Ln;   // segments >= limit never emitted

  const float* hbase = hidden + (size_t)b * Tn * Hn + col;
  float*       obase = out    + (size_t)b * Ln * Hn + col;

  const int seg0 = seg[(size_t)t0 * Bn + b];

  float4 acc    = make_float4(0.f, 0.f, 0.f, 0.f);
  int    curseg = seg0;

  auto flush = [&](int sg, const float4& v, bool shared) {
    if (sg < limit) {
      float* o = obase + (size_t)sg * Hn;
      if (shared) {
        atomicAdd(o + 0, v.x);
        atomicAdd(o + 1, v.y);
        atomicAdd(o + 2, v.z);
        atomicAdd(o + 3, v.w);
      } else {
        *reinterpret_cast<float4*>(o) = v;   // exclusive: plain store
      }
    }
  };

  for (int t = t0; t < t1; ++t) {
    const int s = seg[(size_t)t * Bn + b];
    if (s != curseg) {               // fire with exactly-zero remainder
      flush(curseg, acc, curseg == seg0);
      acc    = make_float4(0.f, 0.f, 0.f, 0.f);
      curseg = s;
    }
    const float4 h = *reinterpret_cast<const float4*>(hbase + (size_t)t * Hn);
    const float2 w = w12[(size_t)t * Bn + b];
    acc.x += w.x * h.x;
    acc.y += w.x * h.y;
    acc.z += w.x * h.z;
    acc.w += w.x * h.w;
    if (w.y != 0.0f) {               // fire: close segment s, open s+1
      flush(s, acc, s == seg0);
      acc.x  = w.y * h.x;
      acc.y  = w.y * h.y;
      acc.z  = w.y * h.z;
      acc.w  = w.y * h.w;
      curseg = s + 1;
    }
  }
  flush(curseg, acc, true);          // open segment: may continue next chunk
}

extern "C" void kernel_launch(void* const* d_in, const int* in_sizes, int n_in,
                              void* d_out, int out_size, void* d_ws, size_t ws_size,
                              hipStream_t stream) {
  const float* hidden = (const float*)d_in[0];
  const float* alphas = (const float*)d_in[1];
  float* out = (float*)d_out;

  // ws layout: w12[T][B] float2 (512 KB) | seg[T][B] i32 (256 KB)
  //          | meta[B][NTCH] float2 (12.8 KB) | fcnt[B] i32
  float2* w12  = (float2*)d_ws;
  int*    segp = (int*)(w12 + (size_t)Bn * Tn);
  float2* meta = (float2*)(segp + (size_t)Bn * Tn);
  int*    fcnt = (int*)(meta + (size_t)Bn * NTCH);

  // Zero d_out with our own full-grid kernel (rocclr fill is ~220 GB/s).
  const int n4 = out_size / 4;   // 16.8 MB -> 1,048,576 float4s
  cif_zero_kernel<<<2048, 256, 0, stream>>>((float4*)out, n4);

  cif_scan_kernel<<<Bn, 64, 0, stream>>>(alphas, meta, fcnt);
  cif_expand_kernel<<<NTCH, 64, 0, stream>>>(alphas, meta, w12, segp);

  dim3 grid(Bn, NTCH);
  cif_accum_kernel<<<grid, 128, 0, stream>>>(hidden, w12, segp, fcnt, out);
}